// Round 1
// baseline (899.280 us; speedup 1.0000x reference)
//
#include <hip/hip_runtime.h>
#include <hip/hip_bf16.h>

typedef __attribute__((ext_vector_type(8))) short short8;
typedef __attribute__((ext_vector_type(4))) float floatx4;

#define B_ROWS 4096
#define N_COLS 8192
#define K_DIM  4096
#define INV_T  10.0f

// round-half-up fp32 -> bf16 pair pack (unbiased enough; ~2^-17 bias)
__device__ __forceinline__ unsigned pack2bf16(float a, float b) {
    unsigned lo = (__float_as_uint(a) + 0x8000u) >> 16;
    unsigned hi = (__float_as_uint(b) + 0x8000u) & 0xFFFF0000u;
    return lo | hi;
}

// K1: diag[i] = 0.5*sims[i,i] + 0.5*dot(im[i], s[i])  (fp32, one block per row)
__global__ __launch_bounds__(256) void diag_kernel(
    const float* __restrict__ im, const float* __restrict__ s,
    const float* __restrict__ sims, float* __restrict__ diag)
{
    const int row = blockIdx.x;
    const float4* a = (const float4*)(im + (size_t)row * K_DIM);
    const float4* b = (const float4*)(s  + (size_t)row * K_DIM);
    float sum = 0.f;
    for (int i = threadIdx.x; i < K_DIM / 4; i += 256) {
        float4 x = a[i], y = b[i];
        sum += x.x * y.x + x.y * y.y + x.z * y.z + x.w * y.w;
    }
    #pragma unroll
    for (int off = 1; off < 64; off <<= 1) sum += __shfl_xor(sum, off, 64);
    __shared__ float wsum[4];
    const int lane = threadIdx.x & 63, wid = threadIdx.x >> 6;
    if (lane == 0) wsum[wid] = sum;
    __syncthreads();
    if (threadIdx.x == 0) {
        float tot = wsum[0] + wsum[1] + wsum[2] + wsum[3];
        diag[row] = 0.5f * sims[(size_t)row * N_COLS + row] + 0.5f * tot;
    }
}

// K2: 128x128-tile bf16 MFMA GEMM with fused epilogue:
//   v = 0.5*sims_local + 0.5*(im@s.T);  second half: v>diag -> 0;  logits = v*10
//   per-tile partial (m, l) for row-lse (i2t, all tiles) and col-lse (t2i, jt<32)
__global__ __launch_bounds__(256) void gemm_loss_kernel(
    const float* __restrict__ im, const float* __restrict__ s,
    const float* __restrict__ sims, const float* __restrict__ diag,
    float* __restrict__ pi2t_m, float* __restrict__ pi2t_l,
    float* __restrict__ pt2i_m, float* __restrict__ pt2i_l)
{
    const int jt = blockIdx.x;   // 0..63 col tile (cols jt*128..)
    const int it = blockIdx.y;   // 0..31 row tile
    const int tid = threadIdx.x;
    const int wid = tid >> 6, lane = tid & 63;
    const int wr = wid >> 1, wc = wid & 1;        // wave 2x2 -> 64x64 each
    const int q = lane >> 4, cl = lane & 15;

    __shared__ __align__(16) unsigned short Asm[128 * 32];
    __shared__ __align__(16) unsigned short Bsm[128 * 32];
    __shared__ float sm_m[2][128], sm_l[2][128];  // [wc][row] i2t cross-wave
    __shared__ float sc_m[2][128], sc_l[2][128];  // [wr][col] t2i cross-wave

    // staging: 512 groups of 8 floats (128 rows x 4 groups), 2 per thread
    const int g0 = tid, g1 = tid + 256;
    const int r0 = g0 >> 2, c0 = (g0 & 3) * 8;
    const int r1 = g1 >> 2, c1 = (g1 & 3) * 8;
    const float* a0 = im + (size_t)(it * 128 + r0) * K_DIM + c0;
    const float* a1 = im + (size_t)(it * 128 + r1) * K_DIM + c1;
    const float* b0 = s  + (size_t)(jt * 128 + r0) * K_DIM + c0;
    const float* b1 = s  + (size_t)(jt * 128 + r1) * K_DIM + c1;
    const int la0 = r0 * 32 + c0, la1 = r1 * 32 + c1;

    floatx4 acc[4][4];
    #pragma unroll
    for (int i = 0; i < 4; ++i)
        #pragma unroll
        for (int j = 0; j < 4; ++j) acc[i][j] = (floatx4){0.f, 0.f, 0.f, 0.f};

    for (int kt = 0; kt < 128; ++kt) {
        float4 xa0 = *(const float4*)a0;
        float4 xa1 = *(const float4*)(a0 + 4);
        float4 ya0 = *(const float4*)a1;
        float4 ya1 = *(const float4*)(a1 + 4);
        float4 xb0 = *(const float4*)b0;
        float4 xb1 = *(const float4*)(b0 + 4);
        float4 yb0 = *(const float4*)b1;
        float4 yb1 = *(const float4*)(b1 + 4);
        a0 += 32; a1 += 32; b0 += 32; b1 += 32;
        __syncthreads();   // previous iteration's LDS reads complete
        *(uint4*)&Asm[la0] = make_uint4(pack2bf16(xa0.x, xa0.y), pack2bf16(xa0.z, xa0.w),
                                        pack2bf16(xa1.x, xa1.y), pack2bf16(xa1.z, xa1.w));
        *(uint4*)&Asm[la1] = make_uint4(pack2bf16(ya0.x, ya0.y), pack2bf16(ya0.z, ya0.w),
                                        pack2bf16(ya1.x, ya1.y), pack2bf16(ya1.z, ya1.w));
        *(uint4*)&Bsm[la0] = make_uint4(pack2bf16(xb0.x, xb0.y), pack2bf16(xb0.z, xb0.w),
                                        pack2bf16(xb1.x, xb1.y), pack2bf16(xb1.z, xb1.w));
        *(uint4*)&Bsm[la1] = make_uint4(pack2bf16(yb0.x, yb0.y), pack2bf16(yb0.z, yb0.w),
                                        pack2bf16(yb1.x, yb1.y), pack2bf16(yb1.z, yb1.w));
        __syncthreads();
        short8 av[4], bv[4];
        #pragma unroll
        for (int ty = 0; ty < 4; ++ty)
            av[ty] = *(const short8*)&Asm[(wr * 64 + ty * 16 + cl) * 32 + q * 8];
        #pragma unroll
        for (int tx = 0; tx < 4; ++tx)
            bv[tx] = *(const short8*)&Bsm[(wc * 64 + tx * 16 + cl) * 32 + q * 8];
        #pragma unroll
        for (int ty = 0; ty < 4; ++ty)
            #pragma unroll
            for (int tx = 0; tx < 4; ++tx)
                acc[ty][tx] = __builtin_amdgcn_mfma_f32_16x16x32_bf16(av[ty], bv[tx], acc[ty][tx], 0, 0, 0);
    }

    // ---------- fused epilogue ----------
    // C/D layout: col = lane&15, row = (lane>>4)*4 + reg  [m89/m91 verified]
    const int row_base = it * 128 + wr * 64;
    const int col_base = jt * 128 + wc * 64;
    const bool second_half = (jt >= 32);

    float dv[4][4];
    #pragma unroll
    for (int ty = 0; ty < 4; ++ty)
        #pragma unroll
        for (int r = 0; r < 4; ++r)
            dv[ty][r] = diag[row_base + ty * 16 + q * 4 + r];

    #pragma unroll
    for (int ty = 0; ty < 4; ++ty) {
        #pragma unroll
        for (int tx = 0; tx < 4; ++tx) {
            const int col = col_base + tx * 16 + cl;
            #pragma unroll
            for (int r = 0; r < 4; ++r) {
                const int row = row_base + ty * 16 + q * 4 + r;
                float v = 0.5f * sims[(size_t)row * N_COLS + col] + 0.5f * acc[ty][tx][r];
                if (second_half && v > dv[ty][r]) v = 0.f;
                acc[ty][tx][r] = v * INV_T;
            }
        }
    }

    // row-wise (i2t): row lives in one quad (16 lanes), 4 cols per lane
    #pragma unroll
    for (int ty = 0; ty < 4; ++ty) {
        #pragma unroll
        for (int r = 0; r < 4; ++r) {
            float mx = fmaxf(fmaxf(acc[ty][0][r], acc[ty][1][r]),
                             fmaxf(acc[ty][2][r], acc[ty][3][r]));
            #pragma unroll
            for (int off = 1; off < 16; off <<= 1) mx = fmaxf(mx, __shfl_xor(mx, off, 64));
            float sum = 0.f;
            #pragma unroll
            for (int tx = 0; tx < 4; ++tx) sum += __expf(acc[ty][tx][r] - mx);
            #pragma unroll
            for (int off = 1; off < 16; off <<= 1) sum += __shfl_xor(sum, off, 64);
            if (cl == 0) {
                sm_m[wc][wr * 64 + ty * 16 + q * 4 + r] = mx;
                sm_l[wc][wr * 64 + ty * 16 + q * 4 + r] = sum;
            }
        }
    }

    // col-wise (t2i): only first-half col tiles; col lives across quads
    if (!second_half) {
        #pragma unroll
        for (int tx = 0; tx < 4; ++tx) {
            float mx = -3.4e38f;
            #pragma unroll
            for (int ty = 0; ty < 4; ++ty)
                #pragma unroll
                for (int r = 0; r < 4; ++r) mx = fmaxf(mx, acc[ty][tx][r]);
            mx = fmaxf(mx, __shfl_xor(mx, 16, 64));
            mx = fmaxf(mx, __shfl_xor(mx, 32, 64));
            float sum = 0.f;
            #pragma unroll
            for (int ty = 0; ty < 4; ++ty)
                #pragma unroll
                for (int r = 0; r < 4; ++r) sum += __expf(acc[ty][tx][r] - mx);
            sum += __shfl_xor(sum, 16, 64);
            sum += __shfl_xor(sum, 32, 64);
            if (q == 0) {
                sc_m[wr][wc * 64 + tx * 16 + cl] = mx;
                sc_l[wr][wc * 64 + tx * 16 + cl] = sum;
            }
        }
    }

    __syncthreads();

    if (tid < 128) {   // combine the 2 column-waves -> per-row (m,l) of this tile
        float m0 = sm_m[0][tid], m1 = sm_m[1][tid];
        float mm = fmaxf(m0, m1);
        float ll = sm_l[0][tid] * __expf(m0 - mm) + sm_l[1][tid] * __expf(m1 - mm);
        pi2t_m[(size_t)jt * B_ROWS + it * 128 + tid] = mm;
        pi2t_l[(size_t)jt * B_ROWS + it * 128 + tid] = ll;
    } else if (!second_half) {  // combine the 2 row-waves -> per-col (m,l)
        const int t2 = tid - 128;
        float m0 = sc_m[0][t2], m1 = sc_m[1][t2];
        float mm = fmaxf(m0, m1);
        float ll = sc_l[0][t2] * __expf(m0 - mm) + sc_l[1][t2] * __expf(m1 - mm);
        pt2i_m[(size_t)it * B_ROWS + jt * 128 + t2] = mm;
        pt2i_l[(size_t)it * B_ROWS + jt * 128 + t2] = ll;
    }
}

// K3: merge partials -> per-row / per-col lse terms, block-reduce, atomic accum
__global__ __launch_bounds__(256) void combine_kernel(
    const float* __restrict__ pi2t_m, const float* __restrict__ pi2t_l,
    const float* __restrict__ pt2i_m, const float* __restrict__ pt2i_l,
    const float* __restrict__ diag, float* __restrict__ accum)
{
    const int gid = blockIdx.x * 256 + threadIdx.x;  // 0..8191
    float term;
    if (gid < B_ROWS) {
        const int row = gid;
        float m = pi2t_m[row], l = pi2t_l[row];
        for (int ct = 1; ct < 64; ++ct) {
            float m2 = pi2t_m[(size_t)ct * B_ROWS + row];
            float l2 = pi2t_l[(size_t)ct * B_ROWS + row];
            float nm = fmaxf(m, m2);
            l = l * __expf(m - nm) + l2 * __expf(m2 - nm);
            m = nm;
        }
        term = m + __logf(l) - diag[row] * INV_T;
    } else {
        const int col = gid - B_ROWS;
        float m = pt2i_m[col], l = pt2i_l[col];
        for (int rt = 1; rt < 32; ++rt) {
            float m2 = pt2i_m[(size_t)rt * B_ROWS + col];
            float l2 = pt2i_l[(size_t)rt * B_ROWS + col];
            float nm = fmaxf(m, m2);
            l = l * __expf(m - nm) + l2 * __expf(m2 - nm);
            m = nm;
        }
        term = m + __logf(l) - diag[col] * INV_T;
    }
    #pragma unroll
    for (int off = 1; off < 64; off <<= 1) term += __shfl_xor(term, off, 64);
    __shared__ float bsum[4];
    if ((threadIdx.x & 63) == 0) bsum[threadIdx.x >> 6] = term;
    __syncthreads();
    if (threadIdx.x == 0) atomicAdd(accum, bsum[0] + bsum[1] + bsum[2] + bsum[3]);
}

__global__ void finalize_kernel(const float* __restrict__ accum, float* __restrict__ out) {
    out[0] = accum[0] * (1.0f / 4096.0f);
}

extern "C" void kernel_launch(void* const* d_in, const int* in_sizes, int n_in,
                              void* d_out, int out_size, void* d_ws, size_t ws_size,
                              hipStream_t stream)
{
    const float* im   = (const float*)d_in[0];   // [4096, 4096]
    const float* s    = (const float*)d_in[1];   // [8192, 4096]
    const float* sims = (const float*)d_in[2];   // [4096, 8192]
    float* out = (float*)d_out;
    float* ws  = (float*)d_ws;

    // workspace layout (floats): total ~790K floats = 3.16 MB
    float* diag   = ws;                       // 4096
    float* pi2t_m = diag + 4096;              // 64 planes x 4096 rows
    float* pi2t_l = pi2t_m + 64 * 4096;
    float* pt2i_m = pi2t_l + 64 * 4096;       // 32 planes x 4096 cols
    float* pt2i_l = pt2i_m + 32 * 4096;
    float* accum  = pt2i_l + 32 * 4096;       // 1

    hipMemsetAsync(accum, 0, sizeof(float), stream);
    diag_kernel<<<4096, 256, 0, stream>>>(im, s, sims, diag);
    gemm_loss_kernel<<<dim3(64, 32), 256, 0, stream>>>(im, s, sims, diag,
                                                       pi2t_m, pi2t_l, pt2i_m, pt2i_l);
    combine_kernel<<<32, 256, 0, stream>>>(pi2t_m, pi2t_l, pt2i_m, pt2i_l, diag, accum);
    finalize_kernel<<<1, 1, 0, stream>>>(accum, out);
}

// Round 2
// 710.369 us; speedup vs baseline: 1.2659x; 1.2659x over previous
//
#include <hip/hip_runtime.h>
#include <hip/hip_bf16.h>

typedef __attribute__((ext_vector_type(8))) short short8;
typedef __attribute__((ext_vector_type(4))) float floatx4;

#define B_ROWS 4096
#define N_COLS 8192
#define K_DIM  4096
#define INV_T  10.0f

// round-half-up fp32 -> bf16 pair pack
__device__ __forceinline__ unsigned pack2bf16(float a, float b) {
    unsigned lo = (__float_as_uint(a) + 0x8000u) >> 16;
    unsigned hi = (__float_as_uint(b) + 0x8000u) & 0xFFFF0000u;
    return lo | hi;
}

// async global->LDS, 16B per lane, LDS dest = wave-uniform base + lane*16
__device__ __forceinline__ void gload_lds16(const void* g, void* l) {
    __builtin_amdgcn_global_load_lds(
        (const __attribute__((address_space(1))) void*)g,
        (__attribute__((address_space(3))) void*)l,
        16, 0, 0);
}

// ---------------------------------------------------------------------------
// K0 (fast path): convert im,s -> bf16 in ws; fused diag computation.
// One block per row of s (8192). Rows < B_ROWS also convert im row + dot.
// ---------------------------------------------------------------------------
__global__ __launch_bounds__(256) void convert_diag_kernel(
    const float* __restrict__ im, const float* __restrict__ s,
    const float* __restrict__ sims,
    unsigned short* __restrict__ im_b, unsigned short* __restrict__ s_b,
    float* __restrict__ diag)
{
    const int row = blockIdx.x;                       // 0..8191
    const float4* srow = (const float4*)(s + (size_t)row * K_DIM);
    uint4* sb = (uint4*)(s_b + (size_t)row * K_DIM);  // 8 bf16 per uint4
    const bool has_im = row < B_ROWS;
    const float4* arow = (const float4*)(im + (size_t)row * K_DIM);
    uint4* ab = (uint4*)(im_b + (size_t)row * K_DIM);

    float sum = 0.f;
    for (int i = threadIdx.x; i < K_DIM / 8; i += 256) {
        float4 y0 = srow[2 * i], y1 = srow[2 * i + 1];
        sb[i] = make_uint4(pack2bf16(y0.x, y0.y), pack2bf16(y0.z, y0.w),
                           pack2bf16(y1.x, y1.y), pack2bf16(y1.z, y1.w));
        if (has_im) {
            float4 x0 = arow[2 * i], x1 = arow[2 * i + 1];
            ab[i] = make_uint4(pack2bf16(x0.x, x0.y), pack2bf16(x0.z, x0.w),
                               pack2bf16(x1.x, x1.y), pack2bf16(x1.z, x1.w));
            sum += x0.x * y0.x + x0.y * y0.y + x0.z * y0.z + x0.w * y0.w;
            sum += x1.x * y1.x + x1.y * y1.y + x1.z * y1.z + x1.w * y1.w;
        }
    }
    if (has_im) {
        #pragma unroll
        for (int off = 1; off < 64; off <<= 1) sum += __shfl_xor(sum, off, 64);
        __shared__ float wsum[4];
        const int lane = threadIdx.x & 63, wid = threadIdx.x >> 6;
        if (lane == 0) wsum[wid] = sum;
        __syncthreads();
        if (threadIdx.x == 0) {
            float tot = wsum[0] + wsum[1] + wsum[2] + wsum[3];
            diag[row] = 0.5f * sims[(size_t)row * N_COLS + row] + 0.5f * tot;
        }
    }
}

// ---------------------------------------------------------------------------
// K1 (fast path): m97-structure bf16 GEMM, 128x128 tile, BK=32,
// global_load_lds width=16, fused loss epilogue.
// ---------------------------------------------------------------------------
__global__ __launch_bounds__(256) void gemm_loss_bf16_kernel(
    const unsigned short* __restrict__ im_b, const unsigned short* __restrict__ s_b,
    const float* __restrict__ sims, const float* __restrict__ diag,
    float* __restrict__ pi2t_m, float* __restrict__ pi2t_l,
    float* __restrict__ pt2i_m, float* __restrict__ pt2i_l)
{
    const int jt = blockIdx.x;   // 0..63 col tile
    const int it = blockIdx.y;   // 0..31 row tile
    const int tid = threadIdx.x;
    const int wid = tid >> 6, lane = tid & 63;
    const int wr = wid >> 1, wc = wid & 1;
    const int q = lane >> 4, cl = lane & 15;

    // LDS: unpadded row-major [128][32] bf16 — required by global_load_lds
    // (wave-uniform base + lane*16; padding would scatter into the pad).
    __shared__ __align__(16) unsigned short Asm[128 * 32];  // 8 KB
    __shared__ __align__(16) unsigned short Bsm[128 * 32];  // 8 KB
    __shared__ float sm_m[2][128], sm_l[2][128];
    __shared__ float sc_m[2][128], sc_l[2][128];

    // staging: wave w, chunk c covers rows (w*2+c)*16..+15, lane l ->
    // row +l/4, k-group (l&3)*8; LDS dest = base(w,c) + l*16 bytes.
    const int r0 = (wid * 2 + 0) * 16 + (lane >> 2);
    const int r1 = (wid * 2 + 1) * 16 + (lane >> 2);
    const int kg = (lane & 3) * 8;
    const unsigned short* gA0 = im_b + (size_t)(it * 128 + r0) * K_DIM + kg;
    const unsigned short* gA1 = im_b + (size_t)(it * 128 + r1) * K_DIM + kg;
    const unsigned short* gB0 = s_b + (size_t)(jt * 128 + r0) * K_DIM + kg;
    const unsigned short* gB1 = s_b + (size_t)(jt * 128 + r1) * K_DIM + kg;
    unsigned short* lA0 = &Asm[(wid * 2 + 0) * 512];
    unsigned short* lA1 = &Asm[(wid * 2 + 1) * 512];
    unsigned short* lB0 = &Bsm[(wid * 2 + 0) * 512];
    unsigned short* lB1 = &Bsm[(wid * 2 + 1) * 512];

    floatx4 acc[4][4];
    #pragma unroll
    for (int i = 0; i < 4; ++i)
        #pragma unroll
        for (int j = 0; j < 4; ++j) acc[i][j] = (floatx4){0.f, 0.f, 0.f, 0.f};

    for (int kt = 0; kt < 128; ++kt) {
        gload_lds16(gA0, lA0);
        gload_lds16(gA1, lA1);
        gload_lds16(gB0, lB0);
        gload_lds16(gB1, lB1);
        gA0 += 32; gA1 += 32; gB0 += 32; gB1 += 32;
        __syncthreads();   // drains vmcnt (loads landed) before ds_read
        short8 av[4], bv[4];
        #pragma unroll
        for (int ty = 0; ty < 4; ++ty)
            av[ty] = *(const short8*)&Asm[(wr * 64 + ty * 16 + cl) * 32 + q * 8];
        #pragma unroll
        for (int tx = 0; tx < 4; ++tx)
            bv[tx] = *(const short8*)&Bsm[(wc * 64 + tx * 16 + cl) * 32 + q * 8];
        #pragma unroll
        for (int ty = 0; ty < 4; ++ty)
            #pragma unroll
            for (int tx = 0; tx < 4; ++tx)
                acc[ty][tx] = __builtin_amdgcn_mfma_f32_16x16x32_bf16(av[ty], bv[tx], acc[ty][tx], 0, 0, 0);
        __syncthreads();   // protect LDS before next iteration overwrites
    }

    // ---------- fused epilogue (identical to verified round-1) ----------
    const int row_base = it * 128 + wr * 64;
    const int col_base = jt * 128 + wc * 64;
    const bool second_half = (jt >= 32);

    float dv[4][4];
    #pragma unroll
    for (int ty = 0; ty < 4; ++ty)
        #pragma unroll
        for (int r = 0; r < 4; ++r)
            dv[ty][r] = diag[row_base + ty * 16 + q * 4 + r];

    #pragma unroll
    for (int ty = 0; ty < 4; ++ty) {
        #pragma unroll
        for (int tx = 0; tx < 4; ++tx) {
            const int col = col_base + tx * 16 + cl;
            #pragma unroll
            for (int r = 0; r < 4; ++r) {
                const int row = row_base + ty * 16 + q * 4 + r;
                float v = 0.5f * sims[(size_t)row * N_COLS + col] + 0.5f * acc[ty][tx][r];
                if (second_half && v > dv[ty][r]) v = 0.f;
                acc[ty][tx][r] = v * INV_T;
            }
        }
    }

    #pragma unroll
    for (int ty = 0; ty < 4; ++ty) {
        #pragma unroll
        for (int r = 0; r < 4; ++r) {
            float mx = fmaxf(fmaxf(acc[ty][0][r], acc[ty][1][r]),
                             fmaxf(acc[ty][2][r], acc[ty][3][r]));
            #pragma unroll
            for (int off = 1; off < 16; off <<= 1) mx = fmaxf(mx, __shfl_xor(mx, off, 64));
            float sum = 0.f;
            #pragma unroll
            for (int tx = 0; tx < 4; ++tx) sum += __expf(acc[ty][tx][r] - mx);
            #pragma unroll
            for (int off = 1; off < 16; off <<= 1) sum += __shfl_xor(sum, off, 64);
            if (cl == 0) {
                sm_m[wc][wr * 64 + ty * 16 + q * 4 + r] = mx;
                sm_l[wc][wr * 64 + ty * 16 + q * 4 + r] = sum;
            }
        }
    }

    if (!second_half) {
        #pragma unroll
        for (int tx = 0; tx < 4; ++tx) {
            float mx = -3.4e38f;
            #pragma unroll
            for (int ty = 0; ty < 4; ++ty)
                #pragma unroll
                for (int r = 0; r < 4; ++r) mx = fmaxf(mx, acc[ty][tx][r]);
            mx = fmaxf(mx, __shfl_xor(mx, 16, 64));
            mx = fmaxf(mx, __shfl_xor(mx, 32, 64));
            float sum = 0.f;
            #pragma unroll
            for (int ty = 0; ty < 4; ++ty)
                #pragma unroll
                for (int r = 0; r < 4; ++r) sum += __expf(acc[ty][tx][r] - mx);
            sum += __shfl_xor(sum, 16, 64);
            sum += __shfl_xor(sum, 32, 64);
            if (q == 0) {
                sc_m[wr][wc * 64 + tx * 16 + cl] = mx;
                sc_l[wr][wc * 64 + tx * 16 + cl] = sum;
            }
        }
    }

    __syncthreads();

    if (tid < 128) {
        float m0 = sm_m[0][tid], m1 = sm_m[1][tid];
        float mm = fmaxf(m0, m1);
        float ll = sm_l[0][tid] * __expf(m0 - mm) + sm_l[1][tid] * __expf(m1 - mm);
        pi2t_m[(size_t)jt * B_ROWS + it * 128 + tid] = mm;
        pi2t_l[(size_t)jt * B_ROWS + it * 128 + tid] = ll;
    } else if (!second_half) {
        const int t2 = tid - 128;
        float m0 = sc_m[0][t2], m1 = sc_m[1][t2];
        float mm = fmaxf(m0, m1);
        float ll = sc_l[0][t2] * __expf(m0 - mm) + sc_l[1][t2] * __expf(m1 - mm);
        pt2i_m[(size_t)it * B_ROWS + jt * 128 + t2] = mm;
        pt2i_l[(size_t)it * B_ROWS + jt * 128 + t2] = ll;
    }
}

// ---------------------------------------------------------------------------
// Fallback path (round-1, fp32 inputs, in-kernel pack) — used if ws too small
// ---------------------------------------------------------------------------
__global__ __launch_bounds__(256) void diag_kernel(
    const float* __restrict__ im, const float* __restrict__ s,
    const float* __restrict__ sims, float* __restrict__ diag)
{
    const int row = blockIdx.x;
    const float4* a = (const float4*)(im + (size_t)row * K_DIM);
    const float4* b = (const float4*)(s  + (size_t)row * K_DIM);
    float sum = 0.f;
    for (int i = threadIdx.x; i < K_DIM / 4; i += 256) {
        float4 x = a[i], y = b[i];
        sum += x.x * y.x + x.y * y.y + x.z * y.z + x.w * y.w;
    }
    #pragma unroll
    for (int off = 1; off < 64; off <<= 1) sum += __shfl_xor(sum, off, 64);
    __shared__ float wsum[4];
    const int lane = threadIdx.x & 63, wid = threadIdx.x >> 6;
    if (lane == 0) wsum[wid] = sum;
    __syncthreads();
    if (threadIdx.x == 0) {
        float tot = wsum[0] + wsum[1] + wsum[2] + wsum[3];
        diag[row] = 0.5f * sims[(size_t)row * N_COLS + row] + 0.5f * tot;
    }
}

__global__ __launch_bounds__(256) void gemm_loss_kernel(
    const float* __restrict__ im, const float* __restrict__ s,
    const float* __restrict__ sims, const float* __restrict__ diag,
    float* __restrict__ pi2t_m, float* __restrict__ pi2t_l,
    float* __restrict__ pt2i_m, float* __restrict__ pt2i_l)
{
    const int jt = blockIdx.x;
    const int it = blockIdx.y;
    const int tid = threadIdx.x;
    const int wid = tid >> 6, lane = tid & 63;
    const int wr = wid >> 1, wc = wid & 1;
    const int q = lane >> 4, cl = lane & 15;

    __shared__ __align__(16) unsigned short Asm[128 * 32];
    __shared__ __align__(16) unsigned short Bsm[128 * 32];
    __shared__ float sm_m[2][128], sm_l[2][128];
    __shared__ float sc_m[2][128], sc_l[2][128];

    const int g0 = tid, g1 = tid + 256;
    const int r0 = g0 >> 2, c0 = (g0 & 3) * 8;
    const int r1 = g1 >> 2, c1 = (g1 & 3) * 8;
    const float* a0 = im + (size_t)(it * 128 + r0) * K_DIM + c0;
    const float* a1 = im + (size_t)(it * 128 + r1) * K_DIM + c1;
    const float* b0 = s  + (size_t)(jt * 128 + r0) * K_DIM + c0;
    const float* b1 = s  + (size_t)(jt * 128 + r1) * K_DIM + c1;
    const int la0 = r0 * 32 + c0, la1 = r1 * 32 + c1;

    floatx4 acc[4][4];
    #pragma unroll
    for (int i = 0; i < 4; ++i)
        #pragma unroll
        for (int j = 0; j < 4; ++j) acc[i][j] = (floatx4){0.f, 0.f, 0.f, 0.f};

    for (int kt = 0; kt < 128; ++kt) {
        float4 xa0 = *(const float4*)a0;
        float4 xa1 = *(const float4*)(a0 + 4);
        float4 ya0 = *(const float4*)a1;
        float4 ya1 = *(const float4*)(a1 + 4);
        float4 xb0 = *(const float4*)b0;
        float4 xb1 = *(const float4*)(b0 + 4);
        float4 yb0 = *(const float4*)b1;
        float4 yb1 = *(const float4*)(b1 + 4);
        a0 += 32; a1 += 32; b0 += 32; b1 += 32;
        __syncthreads();
        *(uint4*)&Asm[la0] = make_uint4(pack2bf16(xa0.x, xa0.y), pack2bf16(xa0.z, xa0.w),
                                        pack2bf16(xa1.x, xa1.y), pack2bf16(xa1.z, xa1.w));
        *(uint4*)&Asm[la1] = make_uint4(pack2bf16(ya0.x, ya0.y), pack2bf16(ya0.z, ya0.w),
                                        pack2bf16(ya1.x, ya1.y), pack2bf16(ya1.z, ya1.w));
        *(uint4*)&Bsm[la0] = make_uint4(pack2bf16(xb0.x, xb0.y), pack2bf16(xb0.z, xb0.w),
                                        pack2bf16(xb1.x, xb1.y), pack2bf16(xb1.z, xb1.w));
        *(uint4*)&Bsm[la1] = make_uint4(pack2bf16(yb0.x, yb0.y), pack2bf16(yb0.z, yb0.w),
                                        pack2bf16(yb1.x, yb1.y), pack2bf16(yb1.z, yb1.w));
        __syncthreads();
        short8 av[4], bv[4];
        #pragma unroll
        for (int ty = 0; ty < 4; ++ty)
            av[ty] = *(const short8*)&Asm[(wr * 64 + ty * 16 + cl) * 32 + q * 8];
        #pragma unroll
        for (int tx = 0; tx < 4; ++tx)
            bv[tx] = *(const short8*)&Bsm[(wc * 64 + tx * 16 + cl) * 32 + q * 8];
        #pragma unroll
        for (int ty = 0; ty < 4; ++ty)
            #pragma unroll
            for (int tx = 0; tx < 4; ++tx)
                acc[ty][tx] = __builtin_amdgcn_mfma_f32_16x16x32_bf16(av[ty], bv[tx], acc[ty][tx], 0, 0, 0);
    }

    const int row_base = it * 128 + wr * 64;
    const int col_base = jt * 128 + wc * 64;
    const bool second_half = (jt >= 32);

    float dv[4][4];
    #pragma unroll
    for (int ty = 0; ty < 4; ++ty)
        #pragma unroll
        for (int r = 0; r < 4; ++r)
            dv[ty][r] = diag[row_base + ty * 16 + q * 4 + r];

    #pragma unroll
    for (int ty = 0; ty < 4; ++ty) {
        #pragma unroll
        for (int tx = 0; tx < 4; ++tx) {
            const int col = col_base + tx * 16 + cl;
            #pragma unroll
            for (int r = 0; r < 4; ++r) {
                const int row = row_base + ty * 16 + q * 4 + r;
                float v = 0.5f * sims[(size_t)row * N_COLS + col] + 0.5f * acc[ty][tx][r];
                if (second_half && v > dv[ty][r]) v = 0.f;
                acc[ty][tx][r] = v * INV_T;
            }
        }
    }

    #pragma unroll
    for (int ty = 0; ty < 4; ++ty) {
        #pragma unroll
        for (int r = 0; r < 4; ++r) {
            float mx = fmaxf(fmaxf(acc[ty][0][r], acc[ty][1][r]),
                             fmaxf(acc[ty][2][r], acc[ty][3][r]));
            #pragma unroll
            for (int off = 1; off < 16; off <<= 1) mx = fmaxf(mx, __shfl_xor(mx, off, 64));
            float sum = 0.f;
            #pragma unroll
            for (int tx = 0; tx < 4; ++tx) sum += __expf(acc[ty][tx][r] - mx);
            #pragma unroll
            for (int off = 1; off < 16; off <<= 1) sum += __shfl_xor(sum, off, 64);
            if (cl == 0) {
                sm_m[wc][wr * 64 + ty * 16 + q * 4 + r] = mx;
                sm_l[wc][wr * 64 + ty * 16 + q * 4 + r] = sum;
            }
        }
    }

    if (!second_half) {
        #pragma unroll
        for (int tx = 0; tx < 4; ++tx) {
            float mx = -3.4e38f;
            #pragma unroll
            for (int ty = 0; ty < 4; ++ty)
                #pragma unroll
                for (int r = 0; r < 4; ++r) mx = fmaxf(mx, acc[ty][tx][r]);
            mx = fmaxf(mx, __shfl_xor(mx, 16, 64));
            mx = fmaxf(mx, __shfl_xor(mx, 32, 64));
            float sum = 0.f;
            #pragma unroll
            for (int ty = 0; ty < 4; ++ty)
                #pragma unroll
                for (int r = 0; r < 4; ++r) sum += __expf(acc[ty][tx][r] - mx);
            sum += __shfl_xor(sum, 16, 64);
            sum += __shfl_xor(sum, 32, 64);
            if (q == 0) {
                sc_m[wr][wc * 64 + tx * 16 + cl] = mx;
                sc_l[wr][wc * 64 + tx * 16 + cl] = sum;
            }
        }
    }

    __syncthreads();

    if (tid < 128) {
        float m0 = sm_m[0][tid], m1 = sm_m[1][tid];
        float mm = fmaxf(m0, m1);
        float ll = sm_l[0][tid] * __expf(m0 - mm) + sm_l[1][tid] * __expf(m1 - mm);
        pi2t_m[(size_t)jt * B_ROWS + it * 128 + tid] = mm;
        pi2t_l[(size_t)jt * B_ROWS + it * 128 + tid] = ll;
    } else if (!second_half) {
        const int t2 = tid - 128;
        float m0 = sc_m[0][t2], m1 = sc_m[1][t2];
        float mm = fmaxf(m0, m1);
        float ll = sc_l[0][t2] * __expf(m0 - mm) + sc_l[1][t2] * __expf(m1 - mm);
        pt2i_m[(size_t)it * B_ROWS + jt * 128 + t2] = mm;
        pt2i_l[(size_t)it * B_ROWS + jt * 128 + t2] = ll;
    }
}

// ---------------------------------------------------------------------------
// K2: merge partials -> per-row / per-col lse terms, block-reduce, atomic accum
// ---------------------------------------------------------------------------
__global__ __launch_bounds__(256) void combine_kernel(
    const float* __restrict__ pi2t_m, const float* __restrict__ pi2t_l,
    const float* __restrict__ pt2i_m, const float* __restrict__ pt2i_l,
    const float* __restrict__ diag, float* __restrict__ accum)
{
    const int gid = blockIdx.x * 256 + threadIdx.x;  // 0..8191
    float term;
    if (gid < B_ROWS) {
        const int row = gid;
        float m = pi2t_m[row], l = pi2t_l[row];
        for (int ct = 1; ct < 64; ++ct) {
            float m2 = pi2t_m[(size_t)ct * B_ROWS + row];
            float l2 = pi2t_l[(size_t)ct * B_ROWS + row];
            float nm = fmaxf(m, m2);
            l = l * __expf(m - nm) + l2 * __expf(m2 - nm);
            m = nm;
        }
        term = m + __logf(l) - diag[row] * INV_T;
    } else {
        const int col = gid - B_ROWS;
        float m = pt2i_m[col], l = pt2i_l[col];
        for (int rt = 1; rt < 32; ++rt) {
            float m2 = pt2i_m[(size_t)rt * B_ROWS + col];
            float l2 = pt2i_l[(size_t)rt * B_ROWS + col];
            float nm = fmaxf(m, m2);
            l = l * __expf(m - nm) + l2 * __expf(m2 - nm);
            m = nm;
        }
        term = m + __logf(l) - diag[col] * INV_T;
    }
    #pragma unroll
    for (int off = 1; off < 64; off <<= 1) term += __shfl_xor(term, off, 64);
    __shared__ float bsum[4];
    if ((threadIdx.x & 63) == 0) bsum[threadIdx.x >> 6] = term;
    __syncthreads();
    if (threadIdx.x == 0) atomicAdd(accum, bsum[0] + bsum[1] + bsum[2] + bsum[3]);
}

__global__ void finalize_kernel(const float* __restrict__ accum, float* __restrict__ out) {
    out[0] = accum[0] * (1.0f / 4096.0f);
}

extern "C" void kernel_launch(void* const* d_in, const int* in_sizes, int n_in,
                              void* d_out, int out_size, void* d_ws, size_t ws_size,
                              hipStream_t stream)
{
    const float* im   = (const float*)d_in[0];   // [4096, 4096]
    const float* s    = (const float*)d_in[1];   // [8192, 4096]
    const float* sims = (const float*)d_in[2];   // [4096, 8192]
    float* out = (float*)d_out;

    const size_t im_b_bytes = (size_t)B_ROWS * K_DIM * 2;   // 32 MB
    const size_t s_b_bytes  = (size_t)N_COLS * K_DIM * 2;   // 64 MB
    const size_t f32_bytes  = (4096 + 2 * 64 * 4096 + 2 * 32 * 4096 + 1) * sizeof(float);
    const size_t need = im_b_bytes + s_b_bytes + f32_bytes;

    if (ws_size >= need) {
        // ---------------- fast path: bf16 materialization + m97 GEMM --------
        unsigned short* im_b = (unsigned short*)d_ws;
        unsigned short* s_b  = (unsigned short*)((char*)d_ws + im_b_bytes);
        float* fbase  = (float*)((char*)d_ws + im_b_bytes + s_b_bytes);
        float* diag   = fbase;
        float* pi2t_m = diag + 4096;
        float* pi2t_l = pi2t_m + 64 * 4096;
        float* pt2i_m = pi2t_l + 64 * 4096;
        float* pt2i_l = pt2i_m + 32 * 4096;
        float* accum  = pt2i_l + 32 * 4096;

        hipMemsetAsync(accum, 0, sizeof(float), stream);
        convert_diag_kernel<<<N_COLS, 256, 0, stream>>>(im, s, sims, im_b, s_b, diag);
        gemm_loss_bf16_kernel<<<dim3(64, 32), 256, 0, stream>>>(im_b, s_b, sims, diag,
                                                                pi2t_m, pi2t_l, pt2i_m, pt2i_l);
        combine_kernel<<<32, 256, 0, stream>>>(pi2t_m, pi2t_l, pt2i_m, pt2i_l, diag, accum);
        finalize_kernel<<<1, 1, 0, stream>>>(accum, out);
    } else {
        // ---------------- fallback: round-1 path ----------------------------
        float* ws = (float*)d_ws;
        float* diag   = ws;
        float* pi2t_m = diag + 4096;
        float* pi2t_l = pi2t_m + 64 * 4096;
        float* pt2i_m = pi2t_l + 64 * 4096;
        float* pt2i_l = pt2i_m + 32 * 4096;
        float* accum  = pt2i_l + 32 * 4096;

        hipMemsetAsync(accum, 0, sizeof(float), stream);
        diag_kernel<<<4096, 256, 0, stream>>>(im, s, sims, diag);
        gemm_loss_kernel<<<dim3(64, 32), 256, 0, stream>>>(im, s, sims, diag,
                                                           pi2t_m, pi2t_l, pt2i_m, pt2i_l);
        combine_kernel<<<32, 256, 0, stream>>>(pi2t_m, pi2t_l, pt2i_m, pt2i_l, diag, accum);
        finalize_kernel<<<1, 1, 0, stream>>>(accum, out);
    }
}

// Round 3
// 678.357 us; speedup vs baseline: 1.3257x; 1.0472x over previous
//
#include <hip/hip_runtime.h>
#include <hip/hip_bf16.h>

typedef __attribute__((ext_vector_type(8))) short short8;
typedef __attribute__((ext_vector_type(4))) float floatx4;

#define B_ROWS 4096
#define N_COLS 8192
#define K_DIM  4096
#define INV_T  10.0f

// round-half-up fp32 -> bf16 pair pack
__device__ __forceinline__ unsigned pack2bf16(float a, float b) {
    unsigned lo = (__float_as_uint(a) + 0x8000u) >> 16;
    unsigned hi = (__float_as_uint(b) + 0x8000u) & 0xFFFF0000u;
    return lo | hi;
}

// async global->LDS, 16B per lane, LDS dest = wave-uniform base + lane*16
__device__ __forceinline__ void gload_lds16(const void* g, void* l) {
    __builtin_amdgcn_global_load_lds(
        (const __attribute__((address_space(1))) void*)g,
        (__attribute__((address_space(3))) void*)l,
        16, 0, 0);
}

// ---------------------------------------------------------------------------
// K0: convert im,s -> bf16 in ws; fused diag computation.
// ---------------------------------------------------------------------------
__global__ __launch_bounds__(256) void convert_diag_kernel(
    const float* __restrict__ im, const float* __restrict__ s,
    const float* __restrict__ sims,
    unsigned short* __restrict__ im_b, unsigned short* __restrict__ s_b,
    float* __restrict__ diag)
{
    const int row = blockIdx.x;                       // 0..8191
    const float4* srow = (const float4*)(s + (size_t)row * K_DIM);
    uint4* sb = (uint4*)(s_b + (size_t)row * K_DIM);
    const bool has_im = row < B_ROWS;
    const float4* arow = (const float4*)(im + (size_t)row * K_DIM);
    uint4* ab = (uint4*)(im_b + (size_t)row * K_DIM);

    float sum = 0.f;
    for (int i = threadIdx.x; i < K_DIM / 8; i += 256) {
        float4 y0 = srow[2 * i], y1 = srow[2 * i + 1];
        sb[i] = make_uint4(pack2bf16(y0.x, y0.y), pack2bf16(y0.z, y0.w),
                           pack2bf16(y1.x, y1.y), pack2bf16(y1.z, y1.w));
        if (has_im) {
            float4 x0 = arow[2 * i], x1 = arow[2 * i + 1];
            ab[i] = make_uint4(pack2bf16(x0.x, x0.y), pack2bf16(x0.z, x0.w),
                               pack2bf16(x1.x, x1.y), pack2bf16(x1.z, x1.w));
            sum += x0.x * y0.x + x0.y * y0.y + x0.z * y0.z + x0.w * y0.w;
            sum += x1.x * y1.x + x1.y * y1.y + x1.z * y1.z + x1.w * y1.w;
        }
    }
    if (has_im) {
        #pragma unroll
        for (int off = 1; off < 64; off <<= 1) sum += __shfl_xor(sum, off, 64);
        __shared__ float wsum[4];
        const int lane = threadIdx.x & 63, wid = threadIdx.x >> 6;
        if (lane == 0) wsum[wid] = sum;
        __syncthreads();
        if (threadIdx.x == 0) {
            float tot = wsum[0] + wsum[1] + wsum[2] + wsum[3];
            diag[row] = 0.5f * sims[(size_t)row * N_COLS + row] + 0.5f * tot;
        }
    }
}

// ---------------------------------------------------------------------------
// K1: bf16 MFMA GEMM, 128x128 tile, BK=32, global_load_lds width=16,
// XOR-swizzled LDS (conflict-free ds_read_b128), double-buffered prefetch
// (loads for k+1 issued after barrier k -> in flight during compute of k),
// fused loss epilogue.
//
// Swizzle: LDS slot s (16B) of row r holds k-group (s ^ ((r>>1)&3)).
// Write side (lane l, HW dest = base + l*16): row = l>>2, slot = l&3
//   -> global k-offset = ((l&3) ^ ((l>>3)&3)) * 8 elements.
//   (permutation within 64B segments: coalescing unchanged)
// Read side: frag (row, q) at row*32 + (q ^ ((row>>1)&3))*8 elements.
//   Bank quad = ((row&1)*4 + (q^((row>>1)&3))) & 7 -> 8 quads x 2 lanes = free.
// ---------------------------------------------------------------------------
__global__ __launch_bounds__(256, 3) void gemm_loss_bf16_kernel(
    const unsigned short* __restrict__ im_b, const unsigned short* __restrict__ s_b,
    const float* __restrict__ sims, const float* __restrict__ diag,
    float* __restrict__ pi2t_m, float* __restrict__ pi2t_l,
    float* __restrict__ pt2i_m, float* __restrict__ pt2i_l)
{
    const int jt = blockIdx.x;   // 0..63 col tile
    const int it = blockIdx.y;   // 0..31 row tile
    const int tid = threadIdx.x;
    const int wid = tid >> 6, lane = tid & 63;
    const int wr = wid >> 1, wc = wid & 1;
    const int q = lane >> 4, cl = lane & 15;

    __shared__ __align__(16) unsigned short Asm[2][128 * 32];  // 2 x 8 KB
    __shared__ __align__(16) unsigned short Bsm[2][128 * 32];  // 2 x 8 KB
    __shared__ float sm_m[2][128], sm_l[2][128];
    __shared__ float sc_m[2][128], sc_l[2][128];

    // staging: wave wid, chunk c covers rows (wid*2+c)*16..+15
    const int r0 = (wid * 2 + 0) * 16 + (lane >> 2);
    const int r1 = (wid * 2 + 1) * 16 + (lane >> 2);
    const int kg = (((lane & 3) ^ ((lane >> 3) & 3))) * 8;   // swizzled k-offset
    const unsigned short* gA0 = im_b + (size_t)(it * 128 + r0) * K_DIM + kg;
    const unsigned short* gA1 = im_b + (size_t)(it * 128 + r1) * K_DIM + kg;
    const unsigned short* gB0 = s_b + (size_t)(jt * 128 + r0) * K_DIM + kg;
    const unsigned short* gB1 = s_b + (size_t)(jt * 128 + r1) * K_DIM + kg;
    const int lo0 = (wid * 2 + 0) * 512;   // wave-uniform LDS element offsets
    const int lo1 = (wid * 2 + 1) * 512;

    // read-side swizzled offsets (elements), invariant over K
    const int swA = (q ^ ((cl >> 1) & 3)) * 8;
    int roffA[4], roffB[4];
    #pragma unroll
    for (int t = 0; t < 4; ++t) {
        roffA[t] = (wr * 64 + t * 16 + cl) * 32 + swA;
        roffB[t] = (wc * 64 + t * 16 + cl) * 32 + swA;
    }

    floatx4 acc[4][4];
    #pragma unroll
    for (int i = 0; i < 4; ++i)
        #pragma unroll
        for (int j = 0; j < 4; ++j) acc[i][j] = (floatx4){0.f, 0.f, 0.f, 0.f};

    // prefetch kt=0 into buffer 0
    gload_lds16(gA0, &Asm[0][lo0]);
    gload_lds16(gA1, &Asm[0][lo1]);
    gload_lds16(gB0, &Bsm[0][lo0]);
    gload_lds16(gB1, &Bsm[0][lo1]);
    gA0 += 32; gA1 += 32; gB0 += 32; gB1 += 32;

    for (int kt = 0; kt < 128; ++kt) {
        const int cur = kt & 1;
        __syncthreads();   // buf[cur] loads landed; prev iter's ds_reads done
        if (kt < 127) {    // prefetch kt+1 into the other buffer (flies during compute)
            const int nxt = cur ^ 1;
            gload_lds16(gA0, &Asm[nxt][lo0]);
            gload_lds16(gA1, &Asm[nxt][lo1]);
            gload_lds16(gB0, &Bsm[nxt][lo0]);
            gload_lds16(gB1, &Bsm[nxt][lo1]);
            gA0 += 32; gA1 += 32; gB0 += 32; gB1 += 32;
        }
        short8 av[4], bv[4];
        #pragma unroll
        for (int ty = 0; ty < 4; ++ty)
            av[ty] = *(const short8*)&Asm[cur][roffA[ty]];
        #pragma unroll
        for (int tx = 0; tx < 4; ++tx)
            bv[tx] = *(const short8*)&Bsm[cur][roffB[tx]];
        #pragma unroll
        for (int ty = 0; ty < 4; ++ty)
            #pragma unroll
            for (int tx = 0; tx < 4; ++tx)
                acc[ty][tx] = __builtin_amdgcn_mfma_f32_16x16x32_bf16(av[ty], bv[tx], acc[ty][tx], 0, 0, 0);
    }

    // ---------- fused epilogue (identical to verified round-1/2) ----------
    const int row_base = it * 128 + wr * 64;
    const int col_base = jt * 128 + wc * 64;
    const bool second_half = (jt >= 32);

    float dv[4][4];
    #pragma unroll
    for (int ty = 0; ty < 4; ++ty)
        #pragma unroll
        for (int r = 0; r < 4; ++r)
            dv[ty][r] = diag[row_base + ty * 16 + q * 4 + r];

    #pragma unroll
    for (int ty = 0; ty < 4; ++ty) {
        #pragma unroll
        for (int tx = 0; tx < 4; ++tx) {
            const int col = col_base + tx * 16 + cl;
            #pragma unroll
            for (int r = 0; r < 4; ++r) {
                const int row = row_base + ty * 16 + q * 4 + r;
                float v = 0.5f * sims[(size_t)row * N_COLS + col] + 0.5f * acc[ty][tx][r];
                if (second_half && v > dv[ty][r]) v = 0.f;
                acc[ty][tx][r] = v * INV_T;
            }
        }
    }

    #pragma unroll
    for (int ty = 0; ty < 4; ++ty) {
        #pragma unroll
        for (int r = 0; r < 4; ++r) {
            float mx = fmaxf(fmaxf(acc[ty][0][r], acc[ty][1][r]),
                             fmaxf(acc[ty][2][r], acc[ty][3][r]));
            #pragma unroll
            for (int off = 1; off < 16; off <<= 1) mx = fmaxf(mx, __shfl_xor(mx, off, 64));
            float sum = 0.f;
            #pragma unroll
            for (int tx = 0; tx < 4; ++tx) sum += __expf(acc[ty][tx][r] - mx);
            #pragma unroll
            for (int off = 1; off < 16; off <<= 1) sum += __shfl_xor(sum, off, 64);
            if (cl == 0) {
                sm_m[wc][wr * 64 + ty * 16 + q * 4 + r] = mx;
                sm_l[wc][wr * 64 + ty * 16 + q * 4 + r] = sum;
            }
        }
    }

    if (!second_half) {
        #pragma unroll
        for (int tx = 0; tx < 4; ++tx) {
            float mx = -3.4e38f;
            #pragma unroll
            for (int ty = 0; ty < 4; ++ty)
                #pragma unroll
                for (int r = 0; r < 4; ++r) mx = fmaxf(mx, acc[ty][tx][r]);
            mx = fmaxf(mx, __shfl_xor(mx, 16, 64));
            mx = fmaxf(mx, __shfl_xor(mx, 32, 64));
            float sum = 0.f;
            #pragma unroll
            for (int ty = 0; ty < 4; ++ty)
                #pragma unroll
                for (int r = 0; r < 4; ++r) sum += __expf(acc[ty][tx][r] - mx);
            sum += __shfl_xor(sum, 16, 64);
            sum += __shfl_xor(sum, 32, 64);
            if (q == 0) {
                sc_m[wr][wc * 64 + tx * 16 + cl] = mx;
                sc_l[wr][wc * 64 + tx * 16 + cl] = sum;
            }
        }
    }

    __syncthreads();

    if (tid < 128) {
        float m0 = sm_m[0][tid], m1 = sm_m[1][tid];
        float mm = fmaxf(m0, m1);
        float ll = sm_l[0][tid] * __expf(m0 - mm) + sm_l[1][tid] * __expf(m1 - mm);
        pi2t_m[(size_t)jt * B_ROWS + it * 128 + tid] = mm;
        pi2t_l[(size_t)jt * B_ROWS + it * 128 + tid] = ll;
    } else if (!second_half) {
        const int t2 = tid - 128;
        float m0 = sc_m[0][t2], m1 = sc_m[1][t2];
        float mm = fmaxf(m0, m1);
        float ll = sc_l[0][t2] * __expf(m0 - mm) + sc_l[1][t2] * __expf(m1 - mm);
        pt2i_m[(size_t)it * B_ROWS + jt * 128 + t2] = mm;
        pt2i_l[(size_t)it * B_ROWS + jt * 128 + t2] = ll;
    }
}

// ---------------------------------------------------------------------------
// Fallback path (round-1, fp32 inputs, in-kernel pack) — used if ws too small
// ---------------------------------------------------------------------------
__global__ __launch_bounds__(256) void diag_kernel(
    const float* __restrict__ im, const float* __restrict__ s,
    const float* __restrict__ sims, float* __restrict__ diag)
{
    const int row = blockIdx.x;
    const float4* a = (const float4*)(im + (size_t)row * K_DIM);
    const float4* b = (const float4*)(s  + (size_t)row * K_DIM);
    float sum = 0.f;
    for (int i = threadIdx.x; i < K_DIM / 4; i += 256) {
        float4 x = a[i], y = b[i];
        sum += x.x * y.x + x.y * y.y + x.z * y.z + x.w * y.w;
    }
    #pragma unroll
    for (int off = 1; off < 64; off <<= 1) sum += __shfl_xor(sum, off, 64);
    __shared__ float wsum[4];
    const int lane = threadIdx.x & 63, wid = threadIdx.x >> 6;
    if (lane == 0) wsum[wid] = sum;
    __syncthreads();
    if (threadIdx.x == 0) {
        float tot = wsum[0] + wsum[1] + wsum[2] + wsum[3];
        diag[row] = 0.5f * sims[(size_t)row * N_COLS + row] + 0.5f * tot;
    }
}

__global__ __launch_bounds__(256) void gemm_loss_kernel(
    const float* __restrict__ im, const float* __restrict__ s,
    const float* __restrict__ sims, const float* __restrict__ diag,
    float* __restrict__ pi2t_m, float* __restrict__ pi2t_l,
    float* __restrict__ pt2i_m, float* __restrict__ pt2i_l)
{
    const int jt = blockIdx.x;
    const int it = blockIdx.y;
    const int tid = threadIdx.x;
    const int wid = tid >> 6, lane = tid & 63;
    const int wr = wid >> 1, wc = wid & 1;
    const int q = lane >> 4, cl = lane & 15;

    __shared__ __align__(16) unsigned short Asm[128 * 32];
    __shared__ __align__(16) unsigned short Bsm[128 * 32];
    __shared__ float sm_m[2][128], sm_l[2][128];
    __shared__ float sc_m[2][128], sc_l[2][128];

    const int g0 = tid, g1 = tid + 256;
    const int r0 = g0 >> 2, c0 = (g0 & 3) * 8;
    const int r1 = g1 >> 2, c1 = (g1 & 3) * 8;
    const float* a0 = im + (size_t)(it * 128 + r0) * K_DIM + c0;
    const float* a1 = im + (size_t)(it * 128 + r1) * K_DIM + c1;
    const float* b0 = s  + (size_t)(jt * 128 + r0) * K_DIM + c0;
    const float* b1 = s  + (size_t)(jt * 128 + r1) * K_DIM + c1;
    const int la0 = r0 * 32 + c0, la1 = r1 * 32 + c1;

    floatx4 acc[4][4];
    #pragma unroll
    for (int i = 0; i < 4; ++i)
        #pragma unroll
        for (int j = 0; j < 4; ++j) acc[i][j] = (floatx4){0.f, 0.f, 0.f, 0.f};

    for (int kt = 0; kt < 128; ++kt) {
        float4 xa0 = *(const float4*)a0;
        float4 xa1 = *(const float4*)(a0 + 4);
        float4 ya0 = *(const float4*)a1;
        float4 ya1 = *(const float4*)(a1 + 4);
        float4 xb0 = *(const float4*)b0;
        float4 xb1 = *(const float4*)(b0 + 4);
        float4 yb0 = *(const float4*)b1;
        float4 yb1 = *(const float4*)(b1 + 4);
        a0 += 32; a1 += 32; b0 += 32; b1 += 32;
        __syncthreads();
        *(uint4*)&Asm[la0] = make_uint4(pack2bf16(xa0.x, xa0.y), pack2bf16(xa0.z, xa0.w),
                                        pack2bf16(xa1.x, xa1.y), pack2bf16(xa1.z, xa1.w));
        *(uint4*)&Asm[la1] = make_uint4(pack2bf16(ya0.x, ya0.y), pack2bf16(ya0.z, ya0.w),
                                        pack2bf16(ya1.x, ya1.y), pack2bf16(ya1.z, ya1.w));
        *(uint4*)&Bsm[la0] = make_uint4(pack2bf16(xb0.x, xb0.y), pack2bf16(xb0.z, xb0.w),
                                        pack2bf16(xb1.x, xb1.y), pack2bf16(xb1.z, xb1.w));
        *(uint4*)&Bsm[la1] = make_uint4(pack2bf16(yb0.x, yb0.y), pack2bf16(yb0.z, yb0.w),
                                        pack2bf16(yb1.x, yb1.y), pack2bf16(yb1.z, yb1.w));
        __syncthreads();
        short8 av[4], bv[4];
        #pragma unroll
        for (int ty = 0; ty < 4; ++ty)
            av[ty] = *(const short8*)&Asm[(wr * 64 + ty * 16 + cl) * 32 + q * 8];
        #pragma unroll
        for (int tx = 0; tx < 4; ++tx)
            bv[tx] = *(const short8*)&Bsm[(wc * 64 + tx * 16 + cl) * 32 + q * 8];
        #pragma unroll
        for (int ty = 0; ty < 4; ++ty)
            #pragma unroll
            for (int tx = 0; tx < 4; ++tx)
                acc[ty][tx] = __builtin_amdgcn_mfma_f32_16x16x32_bf16(av[ty], bv[tx], acc[ty][tx], 0, 0, 0);
    }

    const int row_base = it * 128 + wr * 64;
    const int col_base = jt * 128 + wc * 64;
    const bool second_half = (jt >= 32);

    float dv[4][4];
    #pragma unroll
    for (int ty = 0; ty < 4; ++ty)
        #pragma unroll
        for (int r = 0; r < 4; ++r)
            dv[ty][r] = diag[row_base + ty * 16 + q * 4 + r];

    #pragma unroll
    for (int ty = 0; ty < 4; ++ty) {
        #pragma unroll
        for (int tx = 0; tx < 4; ++tx) {
            const int col = col_base + tx * 16 + cl;
            #pragma unroll
            for (int r = 0; r < 4; ++r) {
                const int row = row_base + ty * 16 + q * 4 + r;
                float v = 0.5f * sims[(size_t)row * N_COLS + col] + 0.5f * acc[ty][tx][r];
                if (second_half && v > dv[ty][r]) v = 0.f;
                acc[ty][tx][r] = v * INV_T;
            }
        }
    }

    #pragma unroll
    for (int ty = 0; ty < 4; ++ty) {
        #pragma unroll
        for (int r = 0; r < 4; ++r) {
            float mx = fmaxf(fmaxf(acc[ty][0][r], acc[ty][1][r]),
                             fmaxf(acc[ty][2][r], acc[ty][3][r]));
            #pragma unroll
            for (int off = 1; off < 16; off <<= 1) mx = fmaxf(mx, __shfl_xor(mx, off, 64));
            float sum = 0.f;
            #pragma unroll
            for (int tx = 0; tx < 4; ++tx) sum += __expf(acc[ty][tx][r] - mx);
            #pragma unroll
            for (int off = 1; off < 16; off <<= 1) sum += __shfl_xor(sum, off, 64);
            if (cl == 0) {
                sm_m[wc][wr * 64 + ty * 16 + q * 4 + r] = mx;
                sm_l[wc][wr * 64 + ty * 16 + q * 4 + r] = sum;
            }
        }
    }

    if (!second_half) {
        #pragma unroll
        for (int tx = 0; tx < 4; ++tx) {
            float mx = -3.4e38f;
            #pragma unroll
            for (int ty = 0; ty < 4; ++ty)
                #pragma unroll
                for (int r = 0; r < 4; ++r) mx = fmaxf(mx, acc[ty][tx][r]);
            mx = fmaxf(mx, __shfl_xor(mx, 16, 64));
            mx = fmaxf(mx, __shfl_xor(mx, 32, 64));
            float sum = 0.f;
            #pragma unroll
            for (int ty = 0; ty < 4; ++ty)
                #pragma unroll
                for (int r = 0; r < 4; ++r) sum += __expf(acc[ty][tx][r] - mx);
            sum += __shfl_xor(sum, 16, 64);
            sum += __shfl_xor(sum, 32, 64);
            if (q == 0) {
                sc_m[wr][wc * 64 + tx * 16 + cl] = mx;
                sc_l[wr][wc * 64 + tx * 16 + cl] = sum;
            }
        }
    }

    __syncthreads();

    if (tid < 128) {
        float m0 = sm_m[0][tid], m1 = sm_m[1][tid];
        float mm = fmaxf(m0, m1);
        float ll = sm_l[0][tid] * __expf(m0 - mm) + sm_l[1][tid] * __expf(m1 - mm);
        pi2t_m[(size_t)jt * B_ROWS + it * 128 + tid] = mm;
        pi2t_l[(size_t)jt * B_ROWS + it * 128 + tid] = ll;
    } else if (!second_half) {
        const int t2 = tid - 128;
        float m0 = sc_m[0][t2], m1 = sc_m[1][t2];
        float mm = fmaxf(m0, m1);
        float ll = sc_l[0][t2] * __expf(m0 - mm) + sc_l[1][t2] * __expf(m1 - mm);
        pt2i_m[(size_t)it * B_ROWS + jt * 128 + t2] = mm;
        pt2i_l[(size_t)it * B_ROWS + jt * 128 + t2] = ll;
    }
}

// ---------------------------------------------------------------------------
// K2: merge partials -> per-row/per-col lse terms, block-reduce -> pblk[32]
// (no atomics, no memset needed)
// ---------------------------------------------------------------------------
__global__ __launch_bounds__(256) void combine_kernel(
    const float* __restrict__ pi2t_m, const float* __restrict__ pi2t_l,
    const float* __restrict__ pt2i_m, const float* __restrict__ pt2i_l,
    const float* __restrict__ diag, float* __restrict__ pblk)
{
    const int gid = blockIdx.x * 256 + threadIdx.x;  // 0..8191
    float term;
    if (gid < B_ROWS) {
        const int row = gid;
        float m = pi2t_m[row], l = pi2t_l[row];
        for (int ct = 1; ct < 64; ++ct) {
            float m2 = pi2t_m[(size_t)ct * B_ROWS + row];
            float l2 = pi2t_l[(size_t)ct * B_ROWS + row];
            float nm = fmaxf(m, m2);
            l = l * __expf(m - nm) + l2 * __expf(m2 - nm);
            m = nm;
        }
        term = m + __logf(l) - diag[row] * INV_T;
    } else {
        const int col = gid - B_ROWS;
        float m = pt2i_m[col], l = pt2i_l[col];
        for (int rt = 1; rt < 32; ++rt) {
            float m2 = pt2i_m[(size_t)rt * B_ROWS + col];
            float l2 = pt2i_l[(size_t)rt * B_ROWS + col];
            float nm = fmaxf(m, m2);
            l = l * __expf(m - nm) + l2 * __expf(m2 - nm);
            m = nm;
        }
        term = m + __logf(l) - diag[col] * INV_T;
    }
    #pragma unroll
    for (int off = 1; off < 64; off <<= 1) term += __shfl_xor(term, off, 64);
    __shared__ float bsum[4];
    if ((threadIdx.x & 63) == 0) bsum[threadIdx.x >> 6] = term;
    __syncthreads();
    if (threadIdx.x == 0) pblk[blockIdx.x] = bsum[0] + bsum[1] + bsum[2] + bsum[3];
}

__global__ void finalize_kernel(const float* __restrict__ pblk, float* __restrict__ out) {
    float v = (threadIdx.x < 32) ? pblk[threadIdx.x] : 0.f;
    #pragma unroll
    for (int off = 1; off < 64; off <<= 1) v += __shfl_xor(v, off, 64);
    if (threadIdx.x == 0) out[0] = v * (1.0f / 4096.0f);
}

extern "C" void kernel_launch(void* const* d_in, const int* in_sizes, int n_in,
                              void* d_out, int out_size, void* d_ws, size_t ws_size,
                              hipStream_t stream)
{
    const float* im   = (const float*)d_in[0];   // [4096, 4096]
    const float* s    = (const float*)d_in[1];   // [8192, 4096]
    const float* sims = (const float*)d_in[2];   // [4096, 8192]
    float* out = (float*)d_out;

    const size_t im_b_bytes = (size_t)B_ROWS * K_DIM * 2;   // 32 MB
    const size_t s_b_bytes  = (size_t)N_COLS * K_DIM * 2;   // 64 MB
    const size_t f32_bytes  = (4096 + 2 * 64 * 4096 + 2 * 32 * 4096 + 32) * sizeof(float);
    const size_t need = im_b_bytes + s_b_bytes + f32_bytes;

    if (ws_size >= need) {
        unsigned short* im_b = (unsigned short*)d_ws;
        unsigned short* s_b  = (unsigned short*)((char*)d_ws + im_b_bytes);
        float* fbase  = (float*)((char*)d_ws + im_b_bytes + s_b_bytes);
        float* diag   = fbase;
        float* pi2t_m = diag + 4096;
        float* pi2t_l = pi2t_m + 64 * 4096;
        float* pt2i_m = pi2t_l + 64 * 4096;
        float* pt2i_l = pt2i_m + 32 * 4096;
        float* pblk   = pt2i_l + 32 * 4096;

        convert_diag_kernel<<<N_COLS, 256, 0, stream>>>(im, s, sims, im_b, s_b, diag);
        gemm_loss_bf16_kernel<<<dim3(64, 32), 256, 0, stream>>>(im_b, s_b, sims, diag,
                                                                pi2t_m, pi2t_l, pt2i_m, pt2i_l);
        combine_kernel<<<32, 256, 0, stream>>>(pi2t_m, pi2t_l, pt2i_m, pt2i_l, diag, pblk);
        finalize_kernel<<<1, 64, 0, stream>>>(pblk, out);
    } else {
        float* ws = (float*)d_ws;
        float* diag   = ws;
        float* pi2t_m = diag + 4096;
        float* pi2t_l = pi2t_m + 64 * 4096;
        float* pt2i_m = pi2t_l + 64 * 4096;
        float* pt2i_l = pt2i_m + 32 * 4096;
        float* pblk   = pt2i_l + 32 * 4096;

        diag_kernel<<<4096, 256, 0, stream>>>(im, s, sims, diag);
        gemm_loss_kernel<<<dim3(64, 32), 256, 0, stream>>>(im, s, sims, diag,
                                                           pi2t_m, pi2t_l, pt2i_m, pt2i_l);
        combine_kernel<<<32, 256, 0, stream>>>(pi2t_m, pi2t_l, pt2i_m, pt2i_l, diag, pblk);
        finalize_kernel<<<1, 64, 0, stream>>>(pblk, out);
    }
}